// Round 4
// baseline (268.354 us; speedup 1.0000x reference)
//
#include <hip/hip_runtime.h>

// PyramidLevel1Block: gather(cur_x by up_idx) ++ pre_x -> GEMM(192x128) -> BN -> ReLU
// B=4, M=65536, N=16384, C_pre=64, C_cur=128, C_in=192, D=128.
//
// Kernel 1: transpose+convert cur_x (B,128,N) fp32 -> curT (B,N,128) bf16 (d_ws)
//           so the per-row gather is 256 B contiguous instead of 128 x 64KB-strided lines.
// Kernel 2: OCCUPANCY-FIRST structure (the R2/R3 lesson: this kernel is
//           latency-bound; 25.6 KB LDS + ~84 VGPR -> 5-6 blocks/CU is the
//           latency-hiding engine; R3's 51 KB LDS halved it and cost 14 us).
//           One 64x192 LDS tile reused across 2 sequential row-tiles.
//           Operand-SWAPPED MFMA (W as A): D = W^T·X^T puts 4 consecutive d per
//           lane -> f32x4 epilogue stores. BN scale folded into W fragments at
//           load time (epilogue = add+ReLU, saves 8 VGPR).

typedef short bhalf8 __attribute__((ext_vector_type(8)));
typedef float f32x4 __attribute__((ext_vector_type(4)));
typedef unsigned int u32x4 __attribute__((ext_vector_type(4)));

__device__ __forceinline__ short f2bf(float f) {
  // round-to-nearest-even float -> bf16 (finite inputs only)
  unsigned int u = __float_as_uint(f);
  unsigned int r = (u + 0x7fffu + ((u >> 16) & 1u)) >> 16;
  return (short)r;
}

// ---------------- Kernel 1: cur_x (B,128,16384) f32 -> curT (B,16384,128) bf16 ---
__global__ __launch_bounds__(256) void transpose_cur(const float* __restrict__ cur,
                                                     short* __restrict__ curT) {
  __shared__ float tile[128][65];  // +1 pad: conflict-free col reads
  const int b = blockIdx.y;
  const int n0 = blockIdx.x << 6;  // 64 n per block
  const float* src = cur + (size_t)b * 128 * 16384;
#pragma unroll
  for (int it = 0; it < 8; ++it) {
    int v = it * 256 + threadIdx.x;
    int cc = v >> 4;
    int nq = (v & 15) << 2;
    f32x4 f = __builtin_nontemporal_load(
        reinterpret_cast<const f32x4*>(&src[(size_t)cc * 16384 + n0 + nq]));
    tile[cc][nq + 0] = f[0];
    tile[cc][nq + 1] = f[1];
    tile[cc][nq + 2] = f[2];
    tile[cc][nq + 3] = f[3];
  }
  __syncthreads();
  short* dst = curT + ((size_t)b * 16384 + n0) * 128;
#pragma unroll
  for (int it = 0; it < 4; ++it) {
    int v = it * 256 + threadIdx.x;
    int nn = v >> 4;
    int c8 = (v & 15) << 3;
    bhalf8 pk;
#pragma unroll
    for (int j = 0; j < 8; ++j) pk[j] = f2bf(tile[c8 + j][nn]);
    *reinterpret_cast<bhalf8*>(&dst[(size_t)nn * 128 + c8]) = pk;
  }
}

// ---------------- Kernel 2: fused gather+GEMM+BN+ReLU -----------------------------
#define NBLK 2048  // row-groups = 4096 (64 rows each), 2 per block

__global__ __launch_bounds__(256, 4) void fused_gemm(
    const float* __restrict__ pre_x,  // (4, 64, 65536)
    const int* __restrict__ up_idx,   // (4, 65536)
    const float* __restrict__ w,      // (192, 128)
    const float* __restrict__ bias,   // (128)
    const float* __restrict__ gamma, const float* __restrict__ beta,
    const float* __restrict__ rmean, const float* __restrict__ rvar,
    const short* __restrict__ curT,  // (4, 16384, 128) bf16
    float* __restrict__ out)         // (4, 65536, 128) f32
{
  // x-tile: 64 rows x 192 k (bf16), row stride 200 shorts (400 B) = 25600 B
  __shared__ short x_lds[64 * 200];
  const int tid = threadIdx.x;
  const int lane = tid & 63;
  const int wv = tid >> 6;    // wave 0..3 -> d cols [32wv, 32wv+32)
  const int c = lane & 15;    // MFMA: A-row(d) / B-col(m) / C-col(m) index
  const int g = lane >> 4;    // MFMA quad: k-group (A/B), d-row group (C)
  const int mrow = tid >> 4;  // 0..15: staging row / idx row
  const int seg = tid & 15;   // 0..15: staging 16B segment / m-quad

  // BN scale for the A-frag column this lane feeds (d = 32wv + 16ct + c);
  // folded into the W fragment so the epilogue is add+ReLU only.
  float scc[2];
#pragma unroll
  for (int ct = 0; ct < 2; ++ct) {
    const int d = 32 * wv + 16 * ct + c;
    scc[ct] = gamma[d] * rsqrtf(rvar[d] + 1e-5f);
  }

  // W fragments in registers, used as MFMA *A* operand (operand-swapped):
  // bf[s][ct][j] = (w[32s + 8g + j][32wv + 16ct + c] * scale_col) as bf16
  bhalf8 bf[6][2];
#pragma unroll
  for (int s = 0; s < 6; ++s)
#pragma unroll
    for (int ct = 0; ct < 2; ++ct) {
      const int col = 32 * wv + 16 * ct + c;
#pragma unroll
      for (int j = 0; j < 8; ++j)
        bf[s][ct][j] = f2bf(w[(32 * s + 8 * g + j) * 128 + col] * scc[ct]);
    }

  // epilogue shift: per-lane f32x4 over d = 32wv + 16ct + 4g + i
  f32x4 shift4[2];
#pragma unroll
  for (int ct = 0; ct < 2; ++ct) {
    const int d0 = 32 * wv + 16 * ct + 4 * g;
    f32x4 gm = *reinterpret_cast<const f32x4*>(&gamma[d0]);
    f32x4 rv = *reinterpret_cast<const f32x4*>(&rvar[d0]);
    f32x4 bs = *reinterpret_cast<const f32x4*>(&bias[d0]);
    f32x4 rm = *reinterpret_cast<const f32x4*>(&rmean[d0]);
    f32x4 bt = *reinterpret_cast<const f32x4*>(&beta[d0]);
#pragma unroll
    for (int i = 0; i < 4; ++i) {
      float sc = gm[i] * rsqrtf(rv[i] + 1e-5f);
      shift4[ct][i] = (bs[i] - rm[i]) * sc + bt[i];
    }
  }

  // hoist both tiles' indices (shortens tile-1's dependent gather chain)
  int idxp[2][4];
#pragma unroll
  for (int t = 0; t < 2; ++t) {
    const long rr = ((long)(blockIdx.x + t * NBLK)) << 6;
#pragma unroll
    for (int it = 0; it < 4; ++it) idxp[t][it] = up_idx[rr + it * 16 + mrow];
  }

  for (int t = 0; t < 2; ++t) {
    const long r0 = ((long)(blockIdx.x + t * NBLK)) << 6;
    const int b = (int)(r0 >> 16);     // / 65536
    const int m0 = (int)(r0 & 65535);  // % 65536 (64-aligned)
    if (t) __syncthreads();  // LDS reuse fence

    // stage: pre_x (f32x4 coalesced along m, transposed to LDS) + gathered rows
    const float* pb = pre_x + (size_t)b * 64 * 65536 + m0;
    f32x4 pr[4];
#pragma unroll
    for (int it = 0; it < 4; ++it)
      pr[it] = __builtin_nontemporal_load(reinterpret_cast<const f32x4*>(
          &pb[(size_t)(it * 16 + mrow) * 65536 + (seg << 2)]));
    u32x4 gt[4];
#pragma unroll
    for (int it = 0; it < 4; ++it)
      gt[it] = *reinterpret_cast<const u32x4*>(
          curT + ((size_t)b * 16384 + idxp[t][it]) * 128 + seg * 8);
#pragma unroll
    for (int it = 0; it < 4; ++it) {
      const int cc = it * 16 + mrow;
      const int mq = seg << 2;
      x_lds[(mq + 0) * 200 + cc] = f2bf(pr[it][0]);
      x_lds[(mq + 1) * 200 + cc] = f2bf(pr[it][1]);
      x_lds[(mq + 2) * 200 + cc] = f2bf(pr[it][2]);
      x_lds[(mq + 3) * 200 + cc] = f2bf(pr[it][3]);
    }
#pragma unroll
    for (int it = 0; it < 4; ++it)
      *reinterpret_cast<u32x4*>(&x_lds[(it * 16 + mrow) * 200 + 64 + seg * 8]) =
          gt[it];
    __syncthreads();

    // compute: operand-swapped MFMA; lane holds m = 16rt + c, d = 32wv+16ct+4g+i
#pragma unroll
    for (int rt = 0; rt < 4; ++rt) {
      bhalf8 a[6];
#pragma unroll
      for (int s = 0; s < 6; ++s)
        a[s] = *reinterpret_cast<const bhalf8*>(
            &x_lds[(16 * rt + c) * 200 + 32 * s + 8 * g]);
      f32x4 acc0 = {0.f, 0.f, 0.f, 0.f};
      f32x4 acc1 = {0.f, 0.f, 0.f, 0.f};
#pragma unroll
      for (int s = 0; s < 6; ++s) {
        acc0 = __builtin_amdgcn_mfma_f32_16x16x32_bf16(bf[s][0], a[s], acc0, 0, 0, 0);
        acc1 = __builtin_amdgcn_mfma_f32_16x16x32_bf16(bf[s][1], a[s], acc1, 0, 0, 0);
      }
      // epilogue: 4 consecutive d per lane -> two 16-B nontemporal stores
      float* ob = out + (size_t)(r0 + 16 * rt + c) * 128 + 32 * wv + 4 * g;
      f32x4 v0, v1;
#pragma unroll
      for (int i = 0; i < 4; ++i) {
        v0[i] = fmaxf(acc0[i] + shift4[0][i], 0.f);
        v1[i] = fmaxf(acc1[i] + shift4[1][i], 0.f);
      }
      __builtin_nontemporal_store(v0, reinterpret_cast<f32x4*>(ob));
      __builtin_nontemporal_store(v1, reinterpret_cast<f32x4*>(ob + 16));
    }
  }
}

extern "C" void kernel_launch(void* const* d_in, const int* in_sizes, int n_in,
                              void* d_out, int out_size, void* d_ws, size_t ws_size,
                              hipStream_t stream) {
  const float* pre_x = (const float*)d_in[0];
  const float* cur_x = (const float*)d_in[1];
  const int* up_idx = (const int*)d_in[2];
  const float* w = (const float*)d_in[3];
  const float* bias = (const float*)d_in[4];
  const float* gamma = (const float*)d_in[5];
  const float* beta = (const float*)d_in[6];
  const float* rmean = (const float*)d_in[7];
  const float* rvar = (const float*)d_in[8];
  float* out = (float*)d_out;
  short* curT = (short*)d_ws;  // (4, 16384, 128) bf16 = 16.8 MB

  hipLaunchKernelGGL(transpose_cur, dim3(256, 4), dim3(256), 0, stream, cur_x, curT);
  hipLaunchKernelGGL(fused_gemm, dim3(NBLK), dim3(256), 0, stream, pre_x, up_idx, w,
                     bias, gamma, beta, rmean, rvar, curT, out);
}

// Round 5
// 235.661 us; speedup vs baseline: 1.1387x; 1.1387x over previous
//
#include <hip/hip_runtime.h>
#include <hip/hip_bf16.h>

// PyramidLevel1Block: gather(cur_x by up_idx) ++ pre_x -> GEMM(192x128) -> BN -> ReLU
// B=4, M=65536, N=16384, C_pre=64, C_cur=128, C_in=192, D=128.
//
// Kernel 1: transpose+convert cur_x (B,128,N) fp32 -> curT (B,N,128) bf16 (d_ws)
//           so the per-row gather is 256 B contiguous instead of 128 x 64KB-strided lines.
// Kernel 2: EXACT R0 baseline structure (fused ~66us; every R2-R4 restructure
//           broke (resident waves) x (per-wave load ILP): (256,2) halved waves,
//           51KB LDS halved blocks, (256,4) squeezed VGPR to 64 and serialized
//           staging). 64 rows/block, x-tile [64][192] bf16 LDS stride 200,
//           W-frags in registers, 16x16x32 bf16 MFMA, fused BN+ReLU epilogue.
// ONE change vs R0: row-keyed XOR swizzle on the pre_x region of the LDS tile
//           (cols 0..63). The b16 staging writes at row-stride 400B hit 2 banks
//           across 64 lanes (32-way conflict, 5.24M conflict-cycles measured);
//           col ^= ((row>>2)&7)<<3 spreads them ~4-way. Reads of a[s], s<2,
//           apply the same XOR (16B-granular: fragments stay contiguous).

typedef short bhalf8 __attribute__((ext_vector_type(8)));
typedef float f32x4 __attribute__((ext_vector_type(4)));
typedef unsigned int u32x4 __attribute__((ext_vector_type(4)));

__device__ __forceinline__ short f2bf(float f) {
  // round-to-nearest-even float -> bf16 (finite inputs only)
  unsigned int u = __float_as_uint(f);
  unsigned int r = (u + 0x7fffu + ((u >> 16) & 1u)) >> 16;
  return (short)r;
}

// ---------------- Kernel 1: cur_x (B,128,16384) f32 -> curT (B,16384,128) bf16 ---
__global__ __launch_bounds__(256) void transpose_cur(const float* __restrict__ cur,
                                                     short* __restrict__ curT) {
  __shared__ float tile[128][65];  // +1 pad: conflict-free col reads
  const int b = blockIdx.y;
  const int n0 = blockIdx.x << 6;  // 64 n per block
  const float* src = cur + (size_t)b * 128 * 16384;
#pragma unroll
  for (int it = 0; it < 8; ++it) {
    int v = it * 256 + threadIdx.x;
    int cc = v >> 4;
    int nq = (v & 15) << 2;
    f32x4 f = __builtin_nontemporal_load(
        reinterpret_cast<const f32x4*>(&src[(size_t)cc * 16384 + n0 + nq]));
    tile[cc][nq + 0] = f[0];
    tile[cc][nq + 1] = f[1];
    tile[cc][nq + 2] = f[2];
    tile[cc][nq + 3] = f[3];
  }
  __syncthreads();
  short* dst = curT + ((size_t)b * 16384 + n0) * 128;
#pragma unroll
  for (int it = 0; it < 4; ++it) {
    int v = it * 256 + threadIdx.x;
    int nn = v >> 4;
    int c8 = (v & 15) << 3;
    bhalf8 pk;
#pragma unroll
    for (int j = 0; j < 8; ++j) pk[j] = f2bf(tile[c8 + j][nn]);
    *reinterpret_cast<bhalf8*>(&dst[(size_t)nn * 128 + c8]) = pk;
  }
}

// ---------------- Kernel 2: fused gather+GEMM+BN+ReLU -----------------------------
#define NBLK 2048  // row-groups = 4096 (64 rows each), 2 per block

__global__ __launch_bounds__(256, 3) void fused_gemm(
    const float* __restrict__ pre_x,  // (4, 64, 65536)
    const int* __restrict__ up_idx,   // (4, 65536)
    const float* __restrict__ w,      // (192, 128)
    const float* __restrict__ bias,   // (128)
    const float* __restrict__ gamma, const float* __restrict__ beta,
    const float* __restrict__ rmean, const float* __restrict__ rvar,
    const short* __restrict__ curT,  // (4, 16384, 128) bf16
    float* __restrict__ out)         // (4, 65536, 128) f32
{
  // x-tile: 64 rows x 192 k (bf16), row stride 200 = 400 B (16B-aligned frags)
  __shared__ short x_lds[64 * 200];
  const int tid = threadIdx.x;
  const int lane = tid & 63;
  const int wv = tid >> 6;    // wave 0..3 -> cols [32wv, 32wv+32)
  const int c = lane & 15;    // MFMA: A-row / C-col / B-col index
  const int g = lane >> 4;    // MFMA quad: k-offset group (A/B), row group (C)

  // W fragments in registers: bf[s][ct][j] = w[32s + 8g + j][32wv + 16ct + c]
  bhalf8 bf[6][2];
#pragma unroll
  for (int s = 0; s < 6; ++s)
#pragma unroll
    for (int ct = 0; ct < 2; ++ct) {
      const int col = 32 * wv + 16 * ct + c;
#pragma unroll
      for (int j = 0; j < 8; ++j)
        bf[s][ct][j] = f2bf(w[(32 * s + 8 * g + j) * 128 + col]);
    }

  // fold bias + BN into y = dot*scale + shift
  float scale[2], shift[2];
#pragma unroll
  for (int ct = 0; ct < 2; ++ct) {
    const int d = 32 * wv + 16 * ct + c;
    float sc = gamma[d] * rsqrtf(rvar[d] + 1e-5f);
    scale[ct] = sc;
    shift[ct] = (bias[d] - rmean[d]) * sc + beta[d];
  }

  for (int t = 0; t < 2; ++t) {
    const long rg = blockIdx.x + (long)t * NBLK;  // row-group id, 64 rows each
    const long r0 = rg << 6;
    const int b = (int)(r0 >> 16);     // / 65536
    const int m0 = (int)(r0 & 65535);  // % 65536 (64-aligned)
    if (t) __syncthreads();  // LDS reuse fence

    // stage pre_x: 64 c x 64 m, coalesced float4 along m, transposed into LDS
    // with row-keyed XOR swizzle on the column (pre region only):
    //   col' = cc ^ ((row>>2)&7)<<3   (16B granular -> frags stay contiguous)
    {
      const float* pb = pre_x + (size_t)b * 64 * 65536 + m0;
#pragma unroll
      for (int it = 0; it < 4; ++it) {
        int v = it * 256 + tid;
        int cc = v >> 4;            // 0..63 channel
        int mq = (v & 15) << 2;     // 0..60 row quad (rows mq..mq+3)
        f32x4 f = __builtin_nontemporal_load(
            reinterpret_cast<const f32x4*>(&pb[(size_t)cc * 65536 + mq]));
        const int swz = ((mq >> 2) & 7) << 3;  // (row>>2)&7 constant over j (j<4)
        const int ccs = cc ^ swz;
        x_lds[(mq + 0) * 200 + ccs] = f2bf(f[0]);
        x_lds[(mq + 1) * 200 + ccs] = f2bf(f[1]);
        x_lds[(mq + 2) * 200 + ccs] = f2bf(f[2]);
        x_lds[(mq + 3) * 200 + ccs] = f2bf(f[3]);
      }
    }
    // stage gathered features: per row, 256 B contiguous from curT[b][idx[r]][:]
    {
#pragma unroll
      for (int it = 0; it < 4; ++it) {
        int mm = it * 16 + (tid >> 4);  // row in tile
        int seg = tid & 15;             // 16 B segment
        int n = up_idx[r0 + mm];
        const short* srcp = curT + ((size_t)b * 16384 + n) * 128 + seg * 8;
        *reinterpret_cast<u32x4*>(&x_lds[mm * 200 + 64 + seg * 8]) =
            *reinterpret_cast<const u32x4*>(srcp);
      }
    }
    __syncthreads();

    // compute: 4 row-tiles x (2 col-tiles of this wave) x 6 k-steps
#pragma unroll
    for (int rt = 0; rt < 4; ++rt) {
      const int row = 16 * rt + c;
      const int rswz = ((row >> 2) & 7) << 3;  // matches staging swizzle
      bhalf8 a[6];
#pragma unroll
      for (int s = 0; s < 6; ++s) {
        const int col = 32 * s + 8 * g;
        const int cols = (s < 2) ? (col ^ rswz) : col;  // pre region swizzled
        a[s] = *reinterpret_cast<const bhalf8*>(&x_lds[row * 200 + cols]);
      }
      f32x4 acc0 = {0.f, 0.f, 0.f, 0.f};
      f32x4 acc1 = {0.f, 0.f, 0.f, 0.f};
#pragma unroll
      for (int s = 0; s < 6; ++s) {
        acc0 = __builtin_amdgcn_mfma_f32_16x16x32_bf16(a[s], bf[s][0], acc0, 0, 0, 0);
        acc1 = __builtin_amdgcn_mfma_f32_16x16x32_bf16(a[s], bf[s][1], acc1, 0, 0, 0);
      }
      // epilogue: C[row=4g+i][col=c], fused scale/shift + ReLU, nontemporal stores
      float* ob = out + (size_t)(r0 + 16 * rt + 4 * g) * 128 + 32 * wv;
#pragma unroll
      for (int i = 0; i < 4; ++i) {
        float v0 = fmaxf(acc0[i] * scale[0] + shift[0], 0.f);
        float v1 = fmaxf(acc1[i] * scale[1] + shift[1], 0.f);
        __builtin_nontemporal_store(v0, ob + (size_t)i * 128 + c);
        __builtin_nontemporal_store(v1, ob + (size_t)i * 128 + 16 + c);
      }
    }
  }
}

extern "C" void kernel_launch(void* const* d_in, const int* in_sizes, int n_in,
                              void* d_out, int out_size, void* d_ws, size_t ws_size,
                              hipStream_t stream) {
  const float* pre_x = (const float*)d_in[0];
  const float* cur_x = (const float*)d_in[1];
  const int* up_idx = (const int*)d_in[2];
  const float* w = (const float*)d_in[3];
  const float* bias = (const float*)d_in[4];
  const float* gamma = (const float*)d_in[5];
  const float* beta = (const float*)d_in[6];
  const float* rmean = (const float*)d_in[7];
  const float* rvar = (const float*)d_in[8];
  float* out = (float*)d_out;
  short* curT = (short*)d_ws;  // (4, 16384, 128) bf16 = 16.8 MB

  hipLaunchKernelGGL(transpose_cur, dim3(256, 4), dim3(256), 0, stream, cur_x, curT);
  hipLaunchKernelGGL(fused_gemm, dim3(NBLK), dim3(256), 0, stream, pre_x, up_idx, w,
                     bias, gamma, beta, rmean, rvar, curT, out);
}

// Round 6
// 233.155 us; speedup vs baseline: 1.1510x; 1.0107x over previous
//
#include <hip/hip_runtime.h>
#include <hip/hip_bf16.h>

// PyramidLevel1Block: gather(cur_x by up_idx) ++ pre_x -> GEMM(192x128) -> BN -> ReLU
// B=4, M=65536, N=16384, C_pre=64, C_cur=128, C_in=192, D=128.
//
// Kernel 1: transpose+convert cur_x (B,128,N) fp32 -> curT (B,N,128) bf16 (d_ws)
//           so the per-row gather is 256 B contiguous instead of 128 x 64KB-strided lines.
// Kernel 2: R0 structure (proven ~66us fused; occupancy x per-wave-ILP is the
//           engine — R2-R4 each broke one factor and regressed).
//           THIS ROUND: gather staging via global_load_lds width=16 (HBM/L2->LDS
//           direct: no staging VGPRs, no ds_writes, loads drain at the barrier).
//           Gather region g_lds[64][128] is LINEAR (wave-uniform base + lane*16,
//           m104 rule); bank conflicts on its 256B-stride reads are fixed by
//           pre-swizzling the per-lane GLOBAL source segment (seg ^ (row&7)) and
//           XORing the same key on reads (both-sides-or-neither, rule #21).
//           pre_x region p_lds[64][72] keeps the R5 write/read swizzle.
//           LDS total 25600 B — identical occupancy to R0/R5.

typedef short bhalf8 __attribute__((ext_vector_type(8)));
typedef float f32x4 __attribute__((ext_vector_type(4)));

__device__ __forceinline__ short f2bf(float f) {
  // round-to-nearest-even float -> bf16 (finite inputs only)
  unsigned int u = __float_as_uint(f);
  unsigned int r = (u + 0x7fffu + ((u >> 16) & 1u)) >> 16;
  return (short)r;
}

__device__ __forceinline__ void gload16(const void* g, void* l) {
  // 16-byte global->LDS direct copy; LDS dest = wave-uniform base + lane*16
  __builtin_amdgcn_global_load_lds(
      (const __attribute__((address_space(1))) unsigned int*)g,
      (__attribute__((address_space(3))) unsigned int*)l, 16, 0, 0);
}

// ---------------- Kernel 1: cur_x (B,128,16384) f32 -> curT (B,16384,128) bf16 ---
__global__ __launch_bounds__(256) void transpose_cur(const float* __restrict__ cur,
                                                     short* __restrict__ curT) {
  __shared__ float tile[128][65];  // +1 pad: conflict-free col reads
  const int b = blockIdx.y;
  const int n0 = blockIdx.x << 6;  // 64 n per block
  const float* src = cur + (size_t)b * 128 * 16384;
#pragma unroll
  for (int it = 0; it < 8; ++it) {
    int v = it * 256 + threadIdx.x;
    int cc = v >> 4;
    int nq = (v & 15) << 2;
    f32x4 f = __builtin_nontemporal_load(
        reinterpret_cast<const f32x4*>(&src[(size_t)cc * 16384 + n0 + nq]));
    tile[cc][nq + 0] = f[0];
    tile[cc][nq + 1] = f[1];
    tile[cc][nq + 2] = f[2];
    tile[cc][nq + 3] = f[3];
  }
  __syncthreads();
  short* dst = curT + ((size_t)b * 16384 + n0) * 128;
#pragma unroll
  for (int it = 0; it < 4; ++it) {
    int v = it * 256 + threadIdx.x;
    int nn = v >> 4;
    int c8 = (v & 15) << 3;
    bhalf8 pk;
#pragma unroll
    for (int j = 0; j < 8; ++j) pk[j] = f2bf(tile[c8 + j][nn]);
    *reinterpret_cast<bhalf8*>(&dst[(size_t)nn * 128 + c8]) = pk;
  }
}

// ---------------- Kernel 2: fused gather+GEMM+BN+ReLU -----------------------------
#define NBLK 2048  // row-groups = 4096 (64 rows each), 2 per block

__global__ __launch_bounds__(256, 3) void fused_gemm(
    const float* __restrict__ pre_x,  // (4, 64, 65536)
    const int* __restrict__ up_idx,   // (4, 65536)
    const float* __restrict__ w,      // (192, 128)
    const float* __restrict__ bias,   // (128)
    const float* __restrict__ gamma, const float* __restrict__ beta,
    const float* __restrict__ rmean, const float* __restrict__ rvar,
    const short* __restrict__ curT,  // (4, 16384, 128) bf16
    float* __restrict__ out)         // (4, 65536, 128) f32
{
  __shared__ short p_lds[64 * 72];   // pre_x: 64 rows x 64 k, stride 72 (9216 B)
  __shared__ short g_lds[64 * 128];  // gather: 64 rows x 128 k, LINEAR 256 B rows
  const int tid = threadIdx.x;
  const int lane = tid & 63;
  const int wv = tid >> 6;    // wave 0..3 -> cols [32wv, 32wv+32)
  const int c = lane & 15;    // MFMA: A-row / C-col / B-col index
  const int g = lane >> 4;    // MFMA quad: k-offset group (A/B), row group (C)
  const int mrow = tid >> 4;  // 0..15: staging row (= 4*wv + (lane>>4))
  const int seg = lane & 15;  // 0..15: 16 B segment within a gathered row
  const int gk = mrow & 7;    // gather swizzle key = row & 7 (it*16 ≡ 0 mod 8)

  // idx first: longest dependent chain (idx -> gather). W/BN work covers it.
  int idxp[2][4];
#pragma unroll
  for (int t = 0; t < 2; ++t) {
    const long rr = ((long)(blockIdx.x + t * NBLK)) << 6;
#pragma unroll
    for (int it = 0; it < 4; ++it) idxp[t][it] = up_idx[rr + it * 16 + mrow];
  }

  // W fragments in registers: bf[s][ct][j] = w[32s + 8g + j][32wv + 16ct + c]
  bhalf8 bf[6][2];
#pragma unroll
  for (int s = 0; s < 6; ++s)
#pragma unroll
    for (int ct = 0; ct < 2; ++ct) {
      const int col = 32 * wv + 16 * ct + c;
#pragma unroll
      for (int j = 0; j < 8; ++j)
        bf[s][ct][j] = f2bf(w[(32 * s + 8 * g + j) * 128 + col]);
    }

  // fold bias + BN into y = dot*scale + shift
  float scale[2], shift[2];
#pragma unroll
  for (int ct = 0; ct < 2; ++ct) {
    const int d = 32 * wv + 16 * ct + c;
    float sc = gamma[d] * rsqrtf(rvar[d] + 1e-5f);
    scale[ct] = sc;
    shift[ct] = (bias[d] - rmean[d]) * sc + beta[d];
  }

  for (int t = 0; t < 2; ++t) {
    const long rg = blockIdx.x + (long)t * NBLK;  // row-group id, 64 rows each
    const long r0 = rg << 6;
    const int b = (int)(r0 >> 16);     // / 65536
    const int m0 = (int)(r0 & 65535);  // % 65536 (64-aligned)
    if (t) __syncthreads();  // LDS reuse fence

    // ---- gather staging FIRST: 4x global_load_lds (no regs, drains at barrier).
    //      Source segment pre-swizzled (seg ^ gk) so the LINEAR LDS write +
    //      swizzled read are the same involution (rule #21).
    {
      const short* cb = curT + (size_t)b * 16384 * 128;
#pragma unroll
      for (int it = 0; it < 4; ++it) {
        const short* srcp = cb + (size_t)idxp[t][it] * 128 + ((seg ^ gk) << 3);
        gload16(srcp, &g_lds[((it * 16 + 4 * wv) << 7)]);  // wave-uniform base
      }
    }
    // ---- pre_x staging: coalesced f32x4 along m, transposed into p_lds with
    //      R5's row-keyed XOR column swizzle (16B-granular).
    {
      const float* pb = pre_x + (size_t)b * 64 * 65536 + m0;
#pragma unroll
      for (int it = 0; it < 4; ++it) {
        int v = it * 256 + tid;
        int cc = v >> 4;            // 0..63 channel
        int mq = (v & 15) << 2;     // row quad (rows mq..mq+3)
        f32x4 f = __builtin_nontemporal_load(
            reinterpret_cast<const f32x4*>(&pb[(size_t)cc * 65536 + mq]));
        const int ccs = cc ^ (((mq >> 2) & 7) << 3);  // key const over the quad
        p_lds[(mq + 0) * 72 + ccs] = f2bf(f[0]);
        p_lds[(mq + 1) * 72 + ccs] = f2bf(f[1]);
        p_lds[(mq + 2) * 72 + ccs] = f2bf(f[2]);
        p_lds[(mq + 3) * 72 + ccs] = f2bf(f[3]);
      }
    }
    __syncthreads();  // drains vmcnt (global_load_lds) + lgkm (ds_writes)

    // compute: 4 row-tiles x (2 col-tiles of this wave) x 6 k-steps
#pragma unroll
    for (int rt = 0; rt < 4; ++rt) {
      const int row = 16 * rt + c;
      const int pswz = ((row >> 2) & 7) << 3;  // p-region key (matches staging)
      const int rgk = row & 7;                 // g-region key (= c & 7)
      bhalf8 a[6];
#pragma unroll
      for (int s = 0; s < 2; ++s)
        a[s] = *reinterpret_cast<const bhalf8*>(
            &p_lds[row * 72 + ((32 * s + 8 * g) ^ pswz)]);
#pragma unroll
      for (int s = 2; s < 6; ++s)
        a[s] = *reinterpret_cast<const bhalf8*>(
            &g_lds[(row << 7) + (((4 * (s - 2) + g) ^ rgk) << 3)]);
      f32x4 acc0 = {0.f, 0.f, 0.f, 0.f};
      f32x4 acc1 = {0.f, 0.f, 0.f, 0.f};
#pragma unroll
      for (int s = 0; s < 6; ++s) {
        acc0 = __builtin_amdgcn_mfma_f32_16x16x32_bf16(a[s], bf[s][0], acc0, 0, 0, 0);
        acc1 = __builtin_amdgcn_mfma_f32_16x16x32_bf16(a[s], bf[s][1], acc1, 0, 0, 0);
      }
      // epilogue: C[row=4g+i][col=c], fused scale/shift + ReLU, nontemporal stores
      float* ob = out + (size_t)(r0 + 16 * rt + 4 * g) * 128 + 32 * wv;
#pragma unroll
      for (int i = 0; i < 4; ++i) {
        float v0 = fmaxf(acc0[i] * scale[0] + shift[0], 0.f);
        float v1 = fmaxf(acc1[i] * scale[1] + shift[1], 0.f);
        __builtin_nontemporal_store(v0, ob + (size_t)i * 128 + c);
        __builtin_nontemporal_store(v1, ob + (size_t)i * 128 + 16 + c);
      }
    }
  }
}

extern "C" void kernel_launch(void* const* d_in, const int* in_sizes, int n_in,
                              void* d_out, int out_size, void* d_ws, size_t ws_size,
                              hipStream_t stream) {
  const float* pre_x = (const float*)d_in[0];
  const float* cur_x = (const float*)d_in[1];
  const int* up_idx = (const int*)d_in[2];
  const float* w = (const float*)d_in[3];
  const float* bias = (const float*)d_in[4];
  const float* gamma = (const float*)d_in[5];
  const float* beta = (const float*)d_in[6];
  const float* rmean = (const float*)d_in[7];
  const float* rvar = (const float*)d_in[8];
  float* out = (float*)d_out;
  short* curT = (short*)d_ws;  // (4, 16384, 128) bf16 = 16.8 MB

  hipLaunchKernelGGL(transpose_cur, dim3(256, 4), dim3(256), 0, stream, cur_x, curT);
  hipLaunchKernelGGL(fused_gemm, dim3(NBLK), dim3(256), 0, stream, pre_x, up_idx, w,
                     bias, gamma, beta, rmean, rvar, curT, out);
}